// Round 11
// baseline (251.244 us; speedup 1.0000x reference)
//
#include <hip/hip_runtime.h>
#include <math.h>

#define BB 64
#define PP 16
#define FIN 672
#define HH 2048
#define AA 32
#define MM (BB*PP)     // 1024
#define EPSBN 1e-5f
#define NKB 21         // FIN/32

// ---- diagnostic repeat factors (idempotent re-execution for profiling) ----
#define REP_PREP  12
#define REP_G1    4
#define REP_G2    24
#define REP_FIN   80

typedef _Float16 f16;
typedef __attribute__((ext_vector_type(8))) _Float16 half8;
typedef __attribute__((ext_vector_type(4))) float floatx4;

__device__ const float LIF_LUT[18] = {
    0.0f,
    0.93750095367431640625f,   // m=1  (0.9375 + 2^-20)
    0.4583339691162109375f,    // m=2
    0.294643402099609375f,     // m=3
    0.21666717529296875f,      // m=4
    0.1713714599609375f,       // m=5
    0.123016357421875f,        // m=6
    0.11712646484375f,         // m=7
    0.0936279296875f,          // m=8
    0.062255859375f,           // m=9
    0.06201171875f,            // m=10
    0.0615234375f,             // m=11
    0.060546875f,              // m=12
    0.05859375f,               // m=13
    0.0546875f,                // m=14
    0.046875f,                 // m=15
    0.03125f,                  // m=16
    0.0f                       // m>=17: no spike
};

// ---------------------------------------------------------------------------
// Fused prep (x12 repeat for profiling visibility).
// ---------------------------------------------------------------------------
__global__ __launch_bounds__(256) void k_prep(
    const float* __restrict__ x, const float* __restrict__ w1,
    const float* __restrict__ g0, const float* __restrict__ b0,
    const float* __restrict__ m0, const float* __restrict__ v0,
    f16* __restrict__ Ah, f16* __restrict__ Al,
    f16* __restrict__ Wh, f16* __restrict__ Wl)
{
    __shared__ float sbuf[32 * 65];
    const int tid = threadIdx.x;
    const int b   = blockIdx.x;

    for (int rep = 0; rep < REP_PREP; ++rep) {
    asm volatile("" ::: "memory");
    if (b < 448) {
        const int mb = b / 7;
        const int kc = b % 7;
        #pragma unroll
        for (int i = 0; i < 2; ++i) {
            const int f4 = tid + 256 * i;
            if (f4 < 384) {
                const int row = f4 / 24;
                const int c4  = (f4 % 24) * 4;
                float4 v = *(const float4*)(x + (size_t)(mb * 16 + row) * FIN + kc * 96 + c4);
                sbuf[row * 97 + c4 + 0] = v.x; sbuf[row * 97 + c4 + 1] = v.y;
                sbuf[row * 97 + c4 + 2] = v.z; sbuf[row * 97 + c4 + 3] = v.w;
            }
        }
        __syncthreads();
        if (tid < 192) {
            const int fi   = tid >> 6;
            const int lane = tid & 63;
            const int row  = lane & 15;
            const int koff = fi * 32 + ((lane >> 4) << 3);
            const float a0  = g0[row] / sqrtf(v0[row] + EPSBN);
            const float be0 = b0[row] - m0[row] * a0;
            half8 hi, lo;
            #pragma unroll
            for (int j = 0; j < 8; ++j) {
                const float xn = fmaf(a0, sbuf[row * 97 + koff + j], be0);
                const f16 h = (f16)xn;
                hi[j] = h;
                lo[j] = (f16)(xn - (float)h);
            }
            const int kb = kc * 3 + fi;
            const size_t idx = ((size_t)(mb * NKB + kb) * 64 + lane);
            *(half8*)(Ah + idx * 8) = hi;
            *(half8*)(Al + idx * 8) = lo;
        }
    } else {
        const int bw = b - 448;
        const int ng = bw & 31;
        const int kb = bw >> 5;
        #pragma unroll
        for (int i = 0; i < 2; ++i) {
            const int f4  = tid + 256 * i;
            const int row = f4 >> 4;
            const int c4  = (f4 & 15) * 4;
            float4 v = *(const float4*)(w1 + (size_t)(kb * 32 + row) * HH + ng * 64 + c4);
            sbuf[row * 65 + c4 + 0] = v.x; sbuf[row * 65 + c4 + 1] = v.y;
            sbuf[row * 65 + c4 + 2] = v.z; sbuf[row * 65 + c4 + 3] = v.w;
        }
        __syncthreads();
        const int fi   = tid >> 6;
        const int lane = tid & 63;
        const int col  = fi * 16 + (lane & 15);
        const int kr   = (lane >> 4) << 3;
        half8 hi, lo;
        #pragma unroll
        for (int j = 0; j < 8; ++j) {
            const float wv = sbuf[(kr + j) * 65 + col];
            const f16 h = (f16)wv;
            hi[j] = h;
            lo[j] = (f16)(wv - (float)h);
        }
        const int nb = ng * 4 + fi;
        const size_t idx = ((size_t)(nb * NKB + kb) * 64 + lane);
        *(half8*)(Wh + idx * 8) = hi;
        *(half8*)(Wl + idx * 8) = lo;
    }
    __syncthreads();
    }
}

// ---------------------------------------------------------------------------
// GEMM1 LDS-staged (x4 repeat for profiling visibility).
// ---------------------------------------------------------------------------
#define GLOAD16(g, l) __builtin_amdgcn_global_load_lds(                        \
    (const __attribute__((address_space(1))) void*)(g),                       \
    (__attribute__((address_space(3))) void*)(l), 16, 0, 0)

__global__ __launch_bounds__(256) void k_gemm1_lds(
    const f16* __restrict__ Ah, const f16* __restrict__ Al,
    const f16* __restrict__ Wh, const f16* __restrict__ Wl,
    const float* __restrict__ bias1,
    const float* __restrict__ g1, const float* __restrict__ b1,
    const float* __restrict__ m1, const float* __restrict__ v1,
    f16* __restrict__ S)
{
    __shared__ __align__(16) char smem[2 * 16 * 1024];

    const int tid  = threadIdx.x;
    const int lane = tid & 63;
    const int w    = tid >> 6;
    const int wm   = w >> 1, wn = w & 1;

    const int b   = blockIdx.x;
    const int xcd = b & 7;
    const int idx = b >> 3;
    const int bm  = (xcd >> 2) * 8 + (idx >> 3);
    const int bn  = (xcd & 3) * 8 + (idx & 7);
    const int mb0 = bm * 4;
    const int nb0 = bn * 4;

    const char* src[4];
    int ldsoff[4];
    #pragma unroll
    for (int q = 0; q < 4; ++q) {
        const int c = w * 4 + q;
        const char* plane; int tile;
        if (c < 4)       { plane = (const char*)Ah; tile = mb0 + c; }
        else if (c < 8)  { plane = (const char*)Al; tile = mb0 + (c - 4); }
        else if (c < 12) { plane = (const char*)Wh; tile = nb0 + (c - 8); }
        else             { plane = (const char*)Wl; tile = nb0 + (c - 12); }
        src[q]    = plane + (size_t)tile * (NKB * 1024) + lane * 16;
        ldsoff[q] = c * 1024;
    }

#define STAGE(kb, bufsel) do {                                                \
    _Pragma("unroll") for (int q_ = 0; q_ < 4; ++q_)                          \
        GLOAD16(src[q_] + (kb) * 1024, smem + (bufsel) * 16384 + ldsoff[q_]); \
} while (0)

    for (int rep = 0; rep < REP_G1; ++rep) {
    asm volatile("" ::: "memory");
    floatx4 acc00 = (floatx4){0.f,0.f,0.f,0.f};
    floatx4 acc01 = (floatx4){0.f,0.f,0.f,0.f};
    floatx4 acc10 = (floatx4){0.f,0.f,0.f,0.f};
    floatx4 acc11 = (floatx4){0.f,0.f,0.f,0.f};

    STAGE(0, 0);
    __syncthreads();

    int cur = 0;
    for (int kb = 0; kb < NKB; ++kb) {
        if (kb + 1 < NKB) STAGE(kb + 1, cur ^ 1);

        const char* base = smem + cur * 16384 + lane * 16;
        half8 ah0 = *(const half8*)(base + (wm * 2 + 0) * 1024);
        half8 ah1 = *(const half8*)(base + (wm * 2 + 1) * 1024);
        half8 al0 = *(const half8*)(base + (4 + wm * 2 + 0) * 1024);
        half8 al1 = *(const half8*)(base + (4 + wm * 2 + 1) * 1024);
        half8 wh0 = *(const half8*)(base + (8 + wn * 2 + 0) * 1024);
        half8 wh1 = *(const half8*)(base + (8 + wn * 2 + 1) * 1024);
        half8 wl0 = *(const half8*)(base + (12 + wn * 2 + 0) * 1024);
        half8 wl1 = *(const half8*)(base + (12 + wn * 2 + 1) * 1024);

        acc00 = __builtin_amdgcn_mfma_f32_16x16x32_f16(ah0, wh0, acc00, 0,0,0);
        acc01 = __builtin_amdgcn_mfma_f32_16x16x32_f16(ah0, wh1, acc01, 0,0,0);
        acc10 = __builtin_amdgcn_mfma_f32_16x16x32_f16(ah1, wh0, acc10, 0,0,0);
        acc11 = __builtin_amdgcn_mfma_f32_16x16x32_f16(ah1, wh1, acc11, 0,0,0);
        acc00 = __builtin_amdgcn_mfma_f32_16x16x32_f16(ah0, wl0, acc00, 0,0,0);
        acc01 = __builtin_amdgcn_mfma_f32_16x16x32_f16(ah0, wl1, acc01, 0,0,0);
        acc10 = __builtin_amdgcn_mfma_f32_16x16x32_f16(ah1, wl0, acc10, 0,0,0);
        acc11 = __builtin_amdgcn_mfma_f32_16x16x32_f16(ah1, wl1, acc11, 0,0,0);
        acc00 = __builtin_amdgcn_mfma_f32_16x16x32_f16(al0, wh0, acc00, 0,0,0);
        acc01 = __builtin_amdgcn_mfma_f32_16x16x32_f16(al0, wh1, acc01, 0,0,0);
        acc10 = __builtin_amdgcn_mfma_f32_16x16x32_f16(al1, wh0, acc10, 0,0,0);
        acc11 = __builtin_amdgcn_mfma_f32_16x16x32_f16(al1, wh1, acc11, 0,0,0);

        __syncthreads();
        cur ^= 1;
    }

    const float H16 = (float)(65536.0 / 65535.0);
    const int   r4  = (lane >> 4) << 2;
    float a1c[4], be1c[4];
    #pragma unroll
    for (int j = 0; j < 4; ++j) {
        const int p = r4 + j;
        a1c[j]  = g1[p] / sqrtf(v1[p] + EPSBN);
        be1c[j] = b1[p] - m1[p] * a1c[j];
    }

    const floatx4 accs[4] = {acc00, acc01, acc10, acc11};
    #pragma unroll
    for (int m = 0; m < 2; ++m) {
        const int rowb = (mb0 + wm * 2 + m) * 16 + r4;
        #pragma unroll
        for (int n = 0; n < 2; ++n) {
            const int col = (nb0 + wn * 2 + n) * 16 + (lane & 15);
            const float bs = bias1[col];
            const floatx4 a4 = accs[m * 2 + n];
            #pragma unroll
            for (int j = 0; j < 4; ++j) {
                const float h = fmaf(a1c[j], a4[j] + bs, be1c[j]);
                float s = 0.f;
                if (h >= H16) {
                    const float rr = 1.f - __builtin_amdgcn_rcpf(h);
                    int mi = (int)ceilf(-__log2f(rr));
                    mi = mi < 1 ? 1 : (mi > 17 ? 17 : mi);
                    s = LIF_LUT[mi];
                }
                S[(size_t)(rowb + j) * HH + col] = (f16)s;
            }
        }
    }
    __syncthreads();
    }
#undef STAGE
}

// ---------------------------------------------------------------------------
// GEMM2 partial (x24 repeat) + finish (x80 repeat).
// ---------------------------------------------------------------------------
__global__ __launch_bounds__(256) void k_gemm2_part(
    const f16* __restrict__ S, const float* __restrict__ w2,
    float* __restrict__ part2)
{
    __shared__ float w2s[8192];
    const int tid = threadIdx.x;
    const int rg  = blockIdx.x;
    const int kc  = blockIdx.y;

    for (int rep = 0; rep < REP_G2; ++rep) {
    asm volatile("" ::: "memory");
    const float4* src = (const float4*)(w2 + (size_t)kc * 8192);
    #pragma unroll
    for (int i = tid; i < 2048; i += 256) ((float4*)w2s)[i] = src[i];
    __syncthreads();

    const int rw  = tid >> 5;
    const int col = tid & 31;
    const int row = rg * 8 + rw;
    const f16* Sp = S + (size_t)row * HH + kc * 256;

    float acc0 = 0.f, acc1 = 0.f;
    #pragma unroll 4
    for (int j = 0; j < 256; j += 8) {
        half8 s8 = *(const half8*)(Sp + j);
        acc0 = fmaf((float)s8[0], w2s[(j + 0) * 32 + col], acc0);
        acc1 = fmaf((float)s8[1], w2s[(j + 1) * 32 + col], acc1);
        acc0 = fmaf((float)s8[2], w2s[(j + 2) * 32 + col], acc0);
        acc1 = fmaf((float)s8[3], w2s[(j + 3) * 32 + col], acc1);
        acc0 = fmaf((float)s8[4], w2s[(j + 4) * 32 + col], acc0);
        acc1 = fmaf((float)s8[5], w2s[(j + 5) * 32 + col], acc1);
        acc0 = fmaf((float)s8[6], w2s[(j + 6) * 32 + col], acc0);
        acc1 = fmaf((float)s8[7], w2s[(j + 7) * 32 + col], acc1);
    }
    part2[((size_t)kc * MM + row) * AA + col] = acc0 + acc1;
    __syncthreads();
    }
}

__global__ __launch_bounds__(256) void k_finish(
    const float* __restrict__ part2, const float* __restrict__ bias2,
    const float* __restrict__ g2, const float* __restrict__ b2,
    const float* __restrict__ m2, const float* __restrict__ v2,
    float* __restrict__ out)
{
    for (int rep = 0; rep < REP_FIN; ++rep) {
    asm volatile("" ::: "memory");
    const int i   = blockIdx.x * 256 + threadIdx.x;
    const int col = i & 31;
    const int row = i >> 5;
    const int p   = row & 15;
    float acc = 0.f;
    #pragma unroll
    for (int s = 0; s < 8; ++s) acc += part2[(size_t)s * MM * AA + i];
    const float a2   = g2[p] / sqrtf(v2[p] + EPSBN);
    const float be2  = b2[p] - m2[p] * a2;
    const float Csum = 0.9375f + 0x1p-20f;
    const float val  = fmaf(a2, acc + Csum * bias2[col], Csum * be2);
    out[i] = 2.0f * tanhf(val);
    }
}

// ---------------------------------------------------------------------------
// Fallback fp32 GEMM1 (used only if ws too small) -> f16 S.  (no repeats)
// ---------------------------------------------------------------------------
__global__ __launch_bounds__(256) void k_gemm1_fp32(
    const float* __restrict__ x, const float* __restrict__ w1,
    const float* __restrict__ bias1,
    const float* __restrict__ g0, const float* __restrict__ b0,
    const float* __restrict__ m0, const float* __restrict__ v0,
    const float* __restrict__ g1, const float* __restrict__ b1,
    const float* __restrict__ m1, const float* __restrict__ v1,
    f16* __restrict__ S)
{
    __shared__ float As[16][36];
    __shared__ float Bs[16][68];

    const int tid = threadIdx.x;
    const int bx  = blockIdx.x;
    const int by  = blockIdx.y;

    const int ar   = tid & 31;
    const int ak   = (tid >> 5) << 1;
    const int grow = by * 32 + ar;
    const int pA   = grow & 15;
    const float a0  = g0[pA] / sqrtf(v0[pA] + EPSBN);
    const float be0 = b0[pA] - m0[pA] * a0;
    const float* xrow = x + (size_t)grow * FIN;

    const int brk = tid >> 4;
    const int bcc = (tid & 15) << 2;
    const float* wp = w1 + (size_t)brk * HH + bx * 64 + bcc;

    const int tx = tid & 15;
    const int ty = tid >> 4;

    float acc[2][4];
    #pragma unroll
    for (int i = 0; i < 2; ++i)
        #pragma unroll
        for (int j = 0; j < 4; ++j) acc[i][j] = 0.f;

    float2 aPre = *(const float2*)(xrow + ak);
    float4 bPre = *(const float4*)(wp);

    for (int kt = 0; kt < FIN; kt += 16) {
        As[ak + 0][ar] = fmaf(a0, aPre.x, be0);
        As[ak + 1][ar] = fmaf(a0, aPre.y, be0);
        *(float4*)&Bs[brk][bcc] = bPre;
        __syncthreads();
        if (kt + 16 < FIN) {
            aPre = *(const float2*)(xrow + kt + 16 + ak);
            bPre = *(const float4*)(wp + (size_t)(kt + 16) * HH);
        }
        #pragma unroll
        for (int k = 0; k < 16; ++k) {
            float2 a2 = *(const float2*)&As[k][ty << 1];
            float4 b4 = *(const float4*)&Bs[k][tx << 2];
            float aa[2] = {a2.x, a2.y};
            float bb[4] = {b4.x, b4.y, b4.z, b4.w};
            #pragma unroll
            for (int i = 0; i < 2; ++i)
                #pragma unroll
                for (int j = 0; j < 4; ++j)
                    acc[i][j] = fmaf(aa[i], bb[j], acc[i][j]);
        }
        __syncthreads();
    }

    const float KC[16] = {
        (1.0f-0x1p-16f)*0.0625f,(1.0f-0x1p-15f)*0.0625f,(1.0f-0x1p-14f)*0.0625f,(1.0f-0x1p-13f)*0.0625f,
        (1.0f-0x1p-12f)*0.0625f,(1.0f-0x1p-11f)*0.0625f,(1.0f-0x1p-10f)*0.0625f,(1.0f-0x1p-9f)*0.0625f,
        (1.0f-0x1p-8f)*0.0625f,(1.0f-0x1p-7f)*0.0625f,(1.0f-0x1p-6f)*0.0625f,(1.0f-0x1p-5f)*0.0625f,
        (1.0f-0x1p-4f)*0.0625f,(1.0f-0x1p-3f)*0.0625f,(1.0f-0x1p-2f)*0.0625f,(1.0f-0x1p-1f)*0.0625f
    };

    const int col0 = bx * 64 + (tx << 2);
    float4 bias4 = *(const float4*)(bias1 + col0);
    const float bias_arr[4] = {bias4.x, bias4.y, bias4.z, bias4.w};

    #pragma unroll
    for (int i = 0; i < 2; ++i) {
        const int r = by * 32 + (ty << 1) + i;
        const int p = r & 15;
        const float a1  = g1[p] / sqrtf(v1[p] + EPSBN);
        const float be1 = b1[p] - m1[p] * a1;
        #pragma unroll
        for (int j = 0; j < 4; ++j) {
            const float h = fmaf(a1, acc[i][j] + bias_arr[j], be1);
            float v = 0.f, s = 0.f;
            #pragma unroll
            for (int t = 0; t < 16; ++t) {
                v = v + (h - v) * 0.5f;
                if (v >= 1.0f) { s += KC[t]; v = 0.f; }
            }
            S[(size_t)r * HH + col0 + j] = (f16)s;
        }
    }
}

extern "C" void kernel_launch(void* const* d_in, const int* in_sizes, int n_in,
                              void* d_out, int out_size, void* d_ws, size_t ws_size,
                              hipStream_t stream) {
    (void)in_sizes; (void)n_in; (void)out_size;
    const float* x     = (const float*)d_in[0];
    const float* w1    = (const float*)d_in[1];
    const float* bias1 = (const float*)d_in[2];
    const float* w2    = (const float*)d_in[3];
    const float* bias2 = (const float*)d_in[4];
    const float* g0 = (const float*)d_in[5];
    const float* b0 = (const float*)d_in[6];
    const float* m0 = (const float*)d_in[7];
    const float* v0 = (const float*)d_in[8];
    const float* g1 = (const float*)d_in[9];
    const float* b1 = (const float*)d_in[10];
    const float* m1 = (const float*)d_in[11];
    const float* v1 = (const float*)d_in[12];
    const float* g2 = (const float*)d_in[13];
    const float* b2 = (const float*)d_in[14];
    const float* m2 = (const float*)d_in[15];
    const float* v2 = (const float*)d_in[16];
    float* out = (float*)d_out;

    const size_t offAl  = 1376256;
    const size_t offWh  = 2752512;
    const size_t offWl  = 5505024;
    const size_t offS   = 8257536;
    const size_t offP2  = offS + 4194304;
    const size_t needed = offP2 + 1048576;   // 13.5 MB

    if (ws_size >= needed) {
        f16* Ah = (f16*)d_ws;
        f16* Al = (f16*)((char*)d_ws + offAl);
        f16* Wh = (f16*)((char*)d_ws + offWh);
        f16* Wl = (f16*)((char*)d_ws + offWl);
        f16* S  = (f16*)((char*)d_ws + offS);
        float* part2 = (float*)((char*)d_ws + offP2);

        k_prep<<<1120, 256, 0, stream>>>(x, w1, g0, b0, m0, v0, Ah, Al, Wh, Wl);
        k_gemm1_lds<<<512, 256, 0, stream>>>(Ah, Al, Wh, Wl, bias1,
                                             g1, b1, m1, v1, S);
        k_gemm2_part<<<dim3(128, 8), 256, 0, stream>>>(S, w2, part2);
        k_finish<<<dim3(128), 256, 0, stream>>>(part2, bias2, g2, b2, m2, v2, out);
    } else {
        f16* S       = (f16*)d_ws;
        float* part2 = (float*)((char*)d_ws + (size_t)MM * HH * sizeof(f16));
        k_gemm1_fp32<<<dim3(32, 32), 256, 0, stream>>>(x, w1, bias1,
                                                       g0, b0, m0, v0,
                                                       g1, b1, m1, v1, S);
        k_gemm2_part<<<dim3(128, 8), 256, 0, stream>>>(S, w2, part2);
        k_finish<<<dim3(128), 256, 0, stream>>>(part2, bias2, g2, b2, m2, v2, out);
    }
}

// Round 12
// 31.065 us; speedup vs baseline: 8.0877x; 8.0877x over previous
//
#include <hip/hip_runtime.h>
#include <math.h>

#define BB 64
#define PP 16
#define FIN 672
#define HH 2048
#define AA 32
#define MM (BB*PP)     // 1024
#define EPSBN 1e-5f
#define NKB 21         // FIN/32

typedef _Float16 f16;
typedef __attribute__((ext_vector_type(8))) _Float16 half8;
typedef __attribute__((ext_vector_type(4))) float floatx4;

// S(h) for the 16-step LIF with constant drive h: spike period m = ceil(-log2(1-1/h)),
// S = sum over spikes q*m<=16 of KC[q*m-1]; exact dyadic values precomputed.
__device__ const float LIF_LUT[18] = {
    0.0f,
    0.93750095367431640625f,   // m=1  (0.9375 + 2^-20)
    0.4583339691162109375f,    // m=2
    0.294643402099609375f,     // m=3
    0.21666717529296875f,      // m=4
    0.1713714599609375f,       // m=5
    0.123016357421875f,        // m=6
    0.11712646484375f,         // m=7
    0.0936279296875f,          // m=8
    0.062255859375f,           // m=9
    0.06201171875f,            // m=10
    0.0615234375f,             // m=11
    0.060546875f,              // m=12
    0.05859375f,               // m=13
    0.0546875f,                // m=14
    0.046875f,                 // m=15
    0.03125f,                  // m=16
    0.0f                       // m>=17: no spike
};

// ---------------------------------------------------------------------------
// Fused prep:
//  blocks [0,448):    A planes  (BN0 + f16 hi/lo, MFMA-A frag order)
//  blocks [448,1120): W1 planes (f16 hi/lo, MFMA-B frag order)
//  blocks [1120,1184): w2 planes (f16 hi/lo, MFMA-B frag order, N=32)
// Frag layout: plane[(tile*NKB + kb)*64 + lane][8 f16] (1 KB per frag chunk);
// w2 planes: [(kb2*2 + nb)*64 + lane][8], kb2 = h/32 (0..63), nb = col/16.
// ---------------------------------------------------------------------------
__global__ __launch_bounds__(256) void k_prep(
    const float* __restrict__ x, const float* __restrict__ w1,
    const float* __restrict__ w2,
    const float* __restrict__ g0, const float* __restrict__ b0,
    const float* __restrict__ m0, const float* __restrict__ v0,
    f16* __restrict__ Ah, f16* __restrict__ Al,
    f16* __restrict__ Wh, f16* __restrict__ Wl,
    f16* __restrict__ W2h, f16* __restrict__ W2l)
{
    __shared__ float sbuf[32 * 65];
    const int tid = threadIdx.x;
    const int b   = blockIdx.x;

    if (b < 448) {
        const int mb = b / 7;
        const int kc = b % 7;
        #pragma unroll
        for (int i = 0; i < 2; ++i) {
            const int f4 = tid + 256 * i;
            if (f4 < 384) {
                const int row = f4 / 24;
                const int c4  = (f4 % 24) * 4;
                float4 v = *(const float4*)(x + (size_t)(mb * 16 + row) * FIN + kc * 96 + c4);
                sbuf[row * 97 + c4 + 0] = v.x; sbuf[row * 97 + c4 + 1] = v.y;
                sbuf[row * 97 + c4 + 2] = v.z; sbuf[row * 97 + c4 + 3] = v.w;
            }
        }
        __syncthreads();
        if (tid < 192) {
            const int fi   = tid >> 6;
            const int lane = tid & 63;
            const int row  = lane & 15;
            const int koff = fi * 32 + ((lane >> 4) << 3);
            const float a0  = g0[row] / sqrtf(v0[row] + EPSBN);
            const float be0 = b0[row] - m0[row] * a0;
            half8 hi, lo;
            #pragma unroll
            for (int j = 0; j < 8; ++j) {
                const float xn = fmaf(a0, sbuf[row * 97 + koff + j], be0);
                const f16 h = (f16)xn;
                hi[j] = h;
                lo[j] = (f16)(xn - (float)h);
            }
            const int kb = kc * 3 + fi;
            const size_t idx = ((size_t)(mb * NKB + kb) * 64 + lane);
            *(half8*)(Ah + idx * 8) = hi;
            *(half8*)(Al + idx * 8) = lo;
        }
    } else if (b < 1120) {
        const int bw = b - 448;
        const int ng = bw & 31;
        const int kb = bw >> 5;
        #pragma unroll
        for (int i = 0; i < 2; ++i) {
            const int f4  = tid + 256 * i;
            const int row = f4 >> 4;
            const int c4  = (f4 & 15) * 4;
            float4 v = *(const float4*)(w1 + (size_t)(kb * 32 + row) * HH + ng * 64 + c4);
            sbuf[row * 65 + c4 + 0] = v.x; sbuf[row * 65 + c4 + 1] = v.y;
            sbuf[row * 65 + c4 + 2] = v.z; sbuf[row * 65 + c4 + 3] = v.w;
        }
        __syncthreads();
        const int fi   = tid >> 6;
        const int lane = tid & 63;
        const int col  = fi * 16 + (lane & 15);
        const int kr   = (lane >> 4) << 3;
        half8 hi, lo;
        #pragma unroll
        for (int j = 0; j < 8; ++j) {
            const float wv = sbuf[(kr + j) * 65 + col];
            const f16 h = (f16)wv;
            hi[j] = h;
            lo[j] = (f16)(wv - (float)h);
        }
        const int nb = ng * 4 + fi;
        const size_t idx = ((size_t)(nb * NKB + kb) * 64 + lane);
        *(half8*)(Wh + idx * 8) = hi;
        *(half8*)(Wl + idx * 8) = lo;
    } else {
        // ---- w2 role: kb2 = 32-h block (64 blocks) ----
        const int kb2 = b - 1120;   // 0..63
        const int row = tid >> 3;   // 0..31
        const int c4  = (tid & 7) << 2;
        float4 v = *(const float4*)(w2 + (size_t)(kb2 * 32 + row) * AA + c4);
        sbuf[row * 33 + c4 + 0] = v.x; sbuf[row * 33 + c4 + 1] = v.y;
        sbuf[row * 33 + c4 + 2] = v.z; sbuf[row * 33 + c4 + 3] = v.w;
        __syncthreads();
        if (tid < 128) {
            const int nb   = tid >> 6;     // 0..1
            const int lane = tid & 63;
            const int col  = nb * 16 + (lane & 15);
            const int kr   = (lane >> 4) << 3;
            half8 hi, lo;
            #pragma unroll
            for (int j = 0; j < 8; ++j) {
                const float wv = sbuf[(kr + j) * 33 + col];
                const f16 h = (f16)wv;
                hi[j] = h;
                lo[j] = (f16)(wv - (float)h);
            }
            const size_t idx = ((size_t)(kb2 * 2 + nb) * 64 + lane);
            *(half8*)(W2h + idx * 8) = hi;
            *(half8*)(W2l + idx * 8) = lo;
        }
    }
}

// ---------------------------------------------------------------------------
// Fused GEMM1 + LIF + GEMM2-partial.
// Per block (bm 0..15, bn 0..31): gemm1 64x64 tile (R10 structure, LDS-staged
// gload_lds dbuf) -> bias1/BN1/LIF-LUT -> S-tile f16 in LDS ->
// 8 MFMAs/wave vs pre-fragged exact w2 (hi+lo) -> part[bn][64x32] fp32.
// Removes the scalar gemm2 kernel (6.8us) + one dispatch + S global traffic.
// ---------------------------------------------------------------------------
#define GLOAD16(g, l) __builtin_amdgcn_global_load_lds(                        \
    (const __attribute__((address_space(1))) void*)(g),                       \
    (__attribute__((address_space(3))) void*)(l), 16, 0, 0)

__global__ __launch_bounds__(256) void k_gemm12(
    const f16* __restrict__ Ah, const f16* __restrict__ Al,
    const f16* __restrict__ Wh, const f16* __restrict__ Wl,
    const f16* __restrict__ W2h, const f16* __restrict__ W2l,
    const float* __restrict__ bias1,
    const float* __restrict__ g1, const float* __restrict__ b1,
    const float* __restrict__ m1, const float* __restrict__ v1,
    float* __restrict__ part)
{
    __shared__ __align__(16) char smem[2 * 16 * 1024];   // 32 KB dbuf / S-tile

    const int tid  = threadIdx.x;
    const int lane = tid & 63;
    const int w    = tid >> 6;
    const int wm   = w >> 1, wn = w & 1;

    const int b   = blockIdx.x;
    const int xcd = b & 7;
    const int idx = b >> 3;
    const int bm  = (xcd >> 2) * 8 + (idx >> 3);   // 0..15
    const int bn  = (xcd & 3) * 8 + (idx & 7);     // 0..31
    const int mb0 = bm * 4;
    const int nb0 = bn * 4;

    const char* src[4];
    int ldsoff[4];
    #pragma unroll
    for (int q = 0; q < 4; ++q) {
        const int c = w * 4 + q;
        const char* plane; int tile;
        if (c < 4)       { plane = (const char*)Ah; tile = mb0 + c; }
        else if (c < 8)  { plane = (const char*)Al; tile = mb0 + (c - 4); }
        else if (c < 12) { plane = (const char*)Wh; tile = nb0 + (c - 8); }
        else             { plane = (const char*)Wl; tile = nb0 + (c - 12); }
        src[q]    = plane + (size_t)tile * (NKB * 1024) + lane * 16;
        ldsoff[q] = c * 1024;
    }

#define STAGE(kb, bufsel) do {                                                \
    _Pragma("unroll") for (int q_ = 0; q_ < 4; ++q_)                          \
        GLOAD16(src[q_] + (kb) * 1024, smem + (bufsel) * 16384 + ldsoff[q_]); \
} while (0)

    floatx4 acc00 = (floatx4){0.f,0.f,0.f,0.f};
    floatx4 acc01 = (floatx4){0.f,0.f,0.f,0.f};
    floatx4 acc10 = (floatx4){0.f,0.f,0.f,0.f};
    floatx4 acc11 = (floatx4){0.f,0.f,0.f,0.f};

    STAGE(0, 0);
    __syncthreads();

    int cur = 0;
    for (int kb = 0; kb < NKB; ++kb) {
        if (kb + 1 < NKB) STAGE(kb + 1, cur ^ 1);

        const char* base = smem + cur * 16384 + lane * 16;
        half8 ah0 = *(const half8*)(base + (wm * 2 + 0) * 1024);
        half8 ah1 = *(const half8*)(base + (wm * 2 + 1) * 1024);
        half8 al0 = *(const half8*)(base + (4 + wm * 2 + 0) * 1024);
        half8 al1 = *(const half8*)(base + (4 + wm * 2 + 1) * 1024);
        half8 wh0 = *(const half8*)(base + (8 + wn * 2 + 0) * 1024);
        half8 wh1 = *(const half8*)(base + (8 + wn * 2 + 1) * 1024);
        half8 wl0 = *(const half8*)(base + (12 + wn * 2 + 0) * 1024);
        half8 wl1 = *(const half8*)(base + (12 + wn * 2 + 1) * 1024);

        acc00 = __builtin_amdgcn_mfma_f32_16x16x32_f16(ah0, wh0, acc00, 0,0,0);
        acc01 = __builtin_amdgcn_mfma_f32_16x16x32_f16(ah0, wh1, acc01, 0,0,0);
        acc10 = __builtin_amdgcn_mfma_f32_16x16x32_f16(ah1, wh0, acc10, 0,0,0);
        acc11 = __builtin_amdgcn_mfma_f32_16x16x32_f16(ah1, wh1, acc11, 0,0,0);
        acc00 = __builtin_amdgcn_mfma_f32_16x16x32_f16(ah0, wl0, acc00, 0,0,0);
        acc01 = __builtin_amdgcn_mfma_f32_16x16x32_f16(ah0, wl1, acc01, 0,0,0);
        acc10 = __builtin_amdgcn_mfma_f32_16x16x32_f16(ah1, wl0, acc10, 0,0,0);
        acc11 = __builtin_amdgcn_mfma_f32_16x16x32_f16(ah1, wl1, acc11, 0,0,0);
        acc00 = __builtin_amdgcn_mfma_f32_16x16x32_f16(al0, wh0, acc00, 0,0,0);
        acc01 = __builtin_amdgcn_mfma_f32_16x16x32_f16(al0, wh1, acc01, 0,0,0);
        acc10 = __builtin_amdgcn_mfma_f32_16x16x32_f16(al1, wh0, acc10, 0,0,0);
        acc11 = __builtin_amdgcn_mfma_f32_16x16x32_f16(al1, wh1, acc11, 0,0,0);

        __syncthreads();
        cur ^= 1;
    }
#undef STAGE

    // ---- bias1 / BN1 / LIF-LUT -> S-tile f16 in LDS [64][72] ----
    f16* Sl = (f16*)smem;
    const float H16 = (float)(65536.0 / 65535.0);
    const int   r4  = (lane >> 4) << 2;
    float a1c[4], be1c[4];
    #pragma unroll
    for (int j = 0; j < 4; ++j) {
        const int p = r4 + j;
        a1c[j]  = g1[p] / sqrtf(v1[p] + EPSBN);
        be1c[j] = b1[p] - m1[p] * a1c[j];
    }

    const floatx4 accs[4] = {acc00, acc01, acc10, acc11};
    #pragma unroll
    for (int m = 0; m < 2; ++m) {
        const int rloc = (wm * 2 + m) * 16 + r4;
        #pragma unroll
        for (int n = 0; n < 2; ++n) {
            const int cloc = (wn * 2 + n) * 16 + (lane & 15);
            const float bs = bias1[nb0 * 16 + cloc];
            const floatx4 a4 = accs[m * 2 + n];
            #pragma unroll
            for (int j = 0; j < 4; ++j) {
                const float h = fmaf(a1c[j], a4[j] + bs, be1c[j]);
                float s = 0.f;
                if (h >= H16) {
                    const float rr = 1.f - __builtin_amdgcn_rcpf(h);
                    int mi = (int)ceilf(-__log2f(rr));
                    mi = mi < 1 ? 1 : (mi > 17 ? 17 : mi);
                    s = LIF_LUT[mi];
                }
                Sl[(rloc + j) * 72 + cloc] = (f16)s;
            }
        }
    }
    __syncthreads();

    // ---- gemm2 partial: wave w owns m-tile w; K = 64 h (2 kb), N = 32 ----
    floatx4 y0 = (floatx4){0.f,0.f,0.f,0.f};
    floatx4 y1 = (floatx4){0.f,0.f,0.f,0.f};
    const int rsl = (w * 16 + (lane & 15)) * 72 + ((lane >> 4) << 3);
    #pragma unroll
    for (int kb = 0; kb < 2; ++kb) {
        half8 sa = *(const half8*)(Sl + rsl + kb * 32);
        const int hb = bn * 2 + kb;
        half8 wh0 = *(const half8*)(W2h + ((size_t)(hb * 2 + 0) * 64 + lane) * 8);
        half8 wh1 = *(const half8*)(W2h + ((size_t)(hb * 2 + 1) * 64 + lane) * 8);
        half8 wl0 = *(const half8*)(W2l + ((size_t)(hb * 2 + 0) * 64 + lane) * 8);
        half8 wl1 = *(const half8*)(W2l + ((size_t)(hb * 2 + 1) * 64 + lane) * 8);
        y0 = __builtin_amdgcn_mfma_f32_16x16x32_f16(sa, wh0, y0, 0,0,0);
        y0 = __builtin_amdgcn_mfma_f32_16x16x32_f16(sa, wl0, y0, 0,0,0);
        y1 = __builtin_amdgcn_mfma_f32_16x16x32_f16(sa, wh1, y1, 0,0,0);
        y1 = __builtin_amdgcn_mfma_f32_16x16x32_f16(sa, wl1, y1, 0,0,0);
    }
    const int prow = bm * 64 + w * 16 + r4;
    float* pp = part + (size_t)bn * (MM * AA) + (size_t)prow * AA + (lane & 15);
    #pragma unroll
    for (int j = 0; j < 4; ++j) {
        pp[j * AA]      = y0[j];
        pp[j * AA + 16] = y1[j];
    }
}

// ---------------------------------------------------------------------------
// Finish: reduce 32 bn-partials + BN2/bias2/ns-LIF-mean + tanh*2.
// ---------------------------------------------------------------------------
__global__ __launch_bounds__(256) void k_finish32(
    const float* __restrict__ part, const float* __restrict__ bias2,
    const float* __restrict__ g2, const float* __restrict__ b2,
    const float* __restrict__ m2, const float* __restrict__ v2,
    float* __restrict__ out)
{
    const int i   = blockIdx.x * 256 + threadIdx.x;
    const int col = i & 31;
    const int row = i >> 5;
    const int p   = row & 15;
    float acc = 0.f;
    #pragma unroll
    for (int s = 0; s < 32; ++s) acc += part[(size_t)s * MM * AA + i];
    const float a2   = g2[p] / sqrtf(v2[p] + EPSBN);
    const float be2  = b2[p] - m2[p] * a2;
    const float Csum = 0.9375f + 0x1p-20f;
    const float val  = fmaf(a2, acc + Csum * bias2[col], Csum * be2);
    out[i] = 2.0f * tanhf(val);
}

// ---------------------------------------------------------------------------
// Fallback path (only if ws too small): fp32 GEMM1 -> f16 S -> scalar gemm2.
// ---------------------------------------------------------------------------
__global__ __launch_bounds__(256) void k_gemm1_fp32(
    const float* __restrict__ x, const float* __restrict__ w1,
    const float* __restrict__ bias1,
    const float* __restrict__ g0, const float* __restrict__ b0,
    const float* __restrict__ m0, const float* __restrict__ v0,
    const float* __restrict__ g1, const float* __restrict__ b1,
    const float* __restrict__ m1, const float* __restrict__ v1,
    f16* __restrict__ S)
{
    __shared__ float As[16][36];
    __shared__ float Bs[16][68];

    const int tid = threadIdx.x;
    const int bx  = blockIdx.x;
    const int by  = blockIdx.y;

    const int ar   = tid & 31;
    const int ak   = (tid >> 5) << 1;
    const int grow = by * 32 + ar;
    const int pA   = grow & 15;
    const float a0  = g0[pA] / sqrtf(v0[pA] + EPSBN);
    const float be0 = b0[pA] - m0[pA] * a0;
    const float* xrow = x + (size_t)grow * FIN;

    const int brk = tid >> 4;
    const int bcc = (tid & 15) << 2;
    const float* wp = w1 + (size_t)brk * HH + bx * 64 + bcc;

    const int tx = tid & 15;
    const int ty = tid >> 4;

    float acc[2][4];
    #pragma unroll
    for (int i = 0; i < 2; ++i)
        #pragma unroll
        for (int j = 0; j < 4; ++j) acc[i][j] = 0.f;

    float2 aPre = *(const float2*)(xrow + ak);
    float4 bPre = *(const float4*)(wp);

    for (int kt = 0; kt < FIN; kt += 16) {
        As[ak + 0][ar] = fmaf(a0, aPre.x, be0);
        As[ak + 1][ar] = fmaf(a0, aPre.y, be0);
        *(float4*)&Bs[brk][bcc] = bPre;
        __syncthreads();
        if (kt + 16 < FIN) {
            aPre = *(const float2*)(xrow + kt + 16 + ak);
            bPre = *(const float4*)(wp + (size_t)(kt + 16) * HH);
        }
        #pragma unroll
        for (int k = 0; k < 16; ++k) {
            float2 a2 = *(const float2*)&As[k][ty << 1];
            float4 b4 = *(const float4*)&Bs[k][tx << 2];
            float aa[2] = {a2.x, a2.y};
            float bb[4] = {b4.x, b4.y, b4.z, b4.w};
            #pragma unroll
            for (int i = 0; i < 2; ++i)
                #pragma unroll
                for (int j = 0; j < 4; ++j)
                    acc[i][j] = fmaf(aa[i], bb[j], acc[i][j]);
        }
        __syncthreads();
    }

    const float KC[16] = {
        (1.0f-0x1p-16f)*0.0625f,(1.0f-0x1p-15f)*0.0625f,(1.0f-0x1p-14f)*0.0625f,(1.0f-0x1p-13f)*0.0625f,
        (1.0f-0x1p-12f)*0.0625f,(1.0f-0x1p-11f)*0.0625f,(1.0f-0x1p-10f)*0.0625f,(1.0f-0x1p-9f)*0.0625f,
        (1.0f-0x1p-8f)*0.0625f,(1.0f-0x1p-7f)*0.0625f,(1.0f-0x1p-6f)*0.0625f,(1.0f-0x1p-5f)*0.0625f,
        (1.0f-0x1p-4f)*0.0625f,(1.0f-0x1p-3f)*0.0625f,(1.0f-0x1p-2f)*0.0625f,(1.0f-0x1p-1f)*0.0625f
    };

    const int col0 = bx * 64 + (tx << 2);
    float4 bias4 = *(const float4*)(bias1 + col0);
    const float bias_arr[4] = {bias4.x, bias4.y, bias4.z, bias4.w};

    #pragma unroll
    for (int i = 0; i < 2; ++i) {
        const int r = by * 32 + (ty << 1) + i;
        const int p = r & 15;
        const float a1  = g1[p] / sqrtf(v1[p] + EPSBN);
        const float be1 = b1[p] - m1[p] * a1;
        #pragma unroll
        for (int j = 0; j < 4; ++j) {
            const float h = fmaf(a1, acc[i][j] + bias_arr[j], be1);
            float v = 0.f, s = 0.f;
            #pragma unroll
            for (int t = 0; t < 16; ++t) {
                v = v + (h - v) * 0.5f;
                if (v >= 1.0f) { s += KC[t]; v = 0.f; }
            }
            S[(size_t)r * HH + col0 + j] = (f16)s;
        }
    }
}

__global__ __launch_bounds__(256) void k_gemm2_part(
    const f16* __restrict__ S, const float* __restrict__ w2,
    float* __restrict__ part2)
{
    __shared__ float w2s[8192];
    const int tid = threadIdx.x;
    const int rg  = blockIdx.x;
    const int kc  = blockIdx.y;

    const float4* src = (const float4*)(w2 + (size_t)kc * 8192);
    #pragma unroll
    for (int i = tid; i < 2048; i += 256) ((float4*)w2s)[i] = src[i];
    __syncthreads();

    const int rw  = tid >> 5;
    const int col = tid & 31;
    const int row = rg * 8 + rw;
    const f16* Sp = S + (size_t)row * HH + kc * 256;

    float acc0 = 0.f, acc1 = 0.f;
    #pragma unroll 4
    for (int j = 0; j < 256; j += 8) {
        half8 s8 = *(const half8*)(Sp + j);
        acc0 = fmaf((float)s8[0], w2s[(j + 0) * 32 + col], acc0);
        acc1 = fmaf((float)s8[1], w2s[(j + 1) * 32 + col], acc1);
        acc0 = fmaf((float)s8[2], w2s[(j + 2) * 32 + col], acc0);
        acc1 = fmaf((float)s8[3], w2s[(j + 3) * 32 + col], acc1);
        acc0 = fmaf((float)s8[4], w2s[(j + 4) * 32 + col], acc0);
        acc1 = fmaf((float)s8[5], w2s[(j + 5) * 32 + col], acc1);
        acc0 = fmaf((float)s8[6], w2s[(j + 6) * 32 + col], acc0);
        acc1 = fmaf((float)s8[7], w2s[(j + 7) * 32 + col], acc1);
    }
    part2[((size_t)kc * MM + row) * AA + col] = acc0 + acc1;
}

__global__ __launch_bounds__(256) void k_finish8(
    const float* __restrict__ part2, const float* __restrict__ bias2,
    const float* __restrict__ g2, const float* __restrict__ b2,
    const float* __restrict__ m2, const float* __restrict__ v2,
    float* __restrict__ out)
{
    const int i   = blockIdx.x * 256 + threadIdx.x;
    const int col = i & 31;
    const int row = i >> 5;
    const int p   = row & 15;
    float acc = 0.f;
    #pragma unroll
    for (int s = 0; s < 8; ++s) acc += part2[(size_t)s * MM * AA + i];
    const float a2   = g2[p] / sqrtf(v2[p] + EPSBN);
    const float be2  = b2[p] - m2[p] * a2;
    const float Csum = 0.9375f + 0x1p-20f;
    const float val  = fmaf(a2, acc + Csum * bias2[col], Csum * be2);
    out[i] = 2.0f * tanhf(val);
}

extern "C" void kernel_launch(void* const* d_in, const int* in_sizes, int n_in,
                              void* d_out, int out_size, void* d_ws, size_t ws_size,
                              hipStream_t stream) {
    (void)in_sizes; (void)n_in; (void)out_size;
    const float* x     = (const float*)d_in[0];
    const float* w1    = (const float*)d_in[1];
    const float* bias1 = (const float*)d_in[2];
    const float* w2    = (const float*)d_in[3];
    const float* bias2 = (const float*)d_in[4];
    const float* g0 = (const float*)d_in[5];
    const float* b0 = (const float*)d_in[6];
    const float* m0 = (const float*)d_in[7];
    const float* v0 = (const float*)d_in[8];
    const float* g1 = (const float*)d_in[9];
    const float* b1 = (const float*)d_in[10];
    const float* m1 = (const float*)d_in[11];
    const float* v1 = (const float*)d_in[12];
    const float* g2 = (const float*)d_in[13];
    const float* b2 = (const float*)d_in[14];
    const float* m2 = (const float*)d_in[15];
    const float* v2 = (const float*)d_in[16];
    float* out = (float*)d_out;

    // ws: Ah 1.31M | Al 1.31M | Wh 2.62M | Wl 2.62M | W2h 128K | W2l 128K | part 4M
    const size_t offAl  = 1376256;
    const size_t offWh  = 2752512;
    const size_t offWl  = 5505024;
    const size_t offW2h = 8257536;
    const size_t offW2l = 8388608;
    const size_t offP   = 8519680;
    const size_t needed = offP + 4194304;   // 12713984

    if (ws_size >= needed) {
        f16* Ah  = (f16*)d_ws;
        f16* Al  = (f16*)((char*)d_ws + offAl);
        f16* Wh  = (f16*)((char*)d_ws + offWh);
        f16* Wl  = (f16*)((char*)d_ws + offWl);
        f16* W2h = (f16*)((char*)d_ws + offW2h);
        f16* W2l = (f16*)((char*)d_ws + offW2l);
        float* part = (float*)((char*)d_ws + offP);

        k_prep<<<1184, 256, 0, stream>>>(x, w1, w2, g0, b0, m0, v0,
                                         Ah, Al, Wh, Wl, W2h, W2l);
        k_gemm12<<<512, 256, 0, stream>>>(Ah, Al, Wh, Wl, W2h, W2l, bias1,
                                          g1, b1, m1, v1, part);
        k_finish32<<<128, 256, 0, stream>>>(part, bias2, g2, b2, m2, v2, out);
    } else {
        f16* S       = (f16*)d_ws;
        float* part2 = (float*)((char*)d_ws + (size_t)MM * HH * sizeof(f16));
        k_gemm1_fp32<<<dim3(32, 32), 256, 0, stream>>>(x, w1, bias1,
                                                       g0, b0, m0, v0,
                                                       g1, b1, m1, v1, S);
        k_gemm2_part<<<dim3(128, 8), 256, 0, stream>>>(S, w2, part2);
        k_finish8<<<128, 256, 0, stream>>>(part2, bias2, g2, b2, m2, v2, out);
    }
}